// Round 17
// baseline (3762.497 us; speedup 1.0000x reference)
//
#include <hip/hip_runtime.h>
#include <hip/hip_bf16.h>

#define NW 256
#define NDEPTH 10
#define NS 25           // shifts per matrix: 250 ldl WGs
#define PAD 12          // stride 48B: 16B-aligned rows, injective bank-groups
#define PIV_EPS 1e-6f   // LDL tiny-pivot guard
#define NLDL (NS * NDEPTH)      // 250 ldl-role blocks
#define NFWD 6                  // forward-role blocks; TOTAL GRID = 256 = one round

// ---------------- bmat: B = (I+W)^T (I+W) + fused max-abs-rowsum ----------------
__global__ __launch_bounds__(256) void bmat_kernel(
    const float* __restrict__ Wb, float* __restrict__ Ball, unsigned int* __restrict__ rsmax) {
  __shared__ float wsum[4][8];
  const int blk = blockIdx.x;
  const int k   = blk >> 5;
  const int r0  = (blk & 31) << 3;
  const int c   = threadIdx.x;
  const float* W = Wb + (size_t)k * NW * NW;
  float acc[8] = {0.f,0.f,0.f,0.f,0.f,0.f,0.f,0.f};
  for (int j = 0; j < NW; ++j) {
    const float wc = W[j * NW + c];
#pragma unroll
    for (int rr = 0; rr < 8; ++rr) acc[rr] += wc * W[j * NW + r0 + rr];
  }
  float a[8];
#pragma unroll
  for (int rr = 0; rr < 8; ++rr) {
    const int r = r0 + rr;
    const float s = acc[rr] + W[c * NW + r] + W[r * NW + c] + ((r == c) ? 1.f : 0.f);
    Ball[(size_t)k * NW * NW + r * NW + c] = s;
    a[rr] = fabsf(s);
  }
#pragma unroll
  for (int off = 32; off; off >>= 1) {
#pragma unroll
    for (int rr = 0; rr < 8; ++rr) a[rr] += __shfl_down(a[rr], off);
  }
  if ((c & 63) == 0) {
#pragma unroll
    for (int rr = 0; rr < 8; ++rr) wsum[c >> 6][rr] = a[rr];
  }
  __syncthreads();
  if (c == 0) {
    float mx = 0.f;
#pragma unroll
    for (int rr = 0; rr < 8; ++rr)
      mx = fmaxf(mx, wsum[0][rr] + wsum[1][rr] + wsum[2][rr] + wsum[3][rr]);
    atomicMax(&rsmax[k], __float_as_uint(mx));
  }
}

// ---------------- fused ldl + forward: 250 ldl + 6 forward = 256 WGs ----------------
// ldl body byte-identical to the validated R14 form. REGISTER CLIFF (R11/R13/
// R15 errata): adding live state to the ldl loop spills the AGPR-resident tile
// (FETCH_SIZE MB->GB, 3-12x). GRID LAW (R16 erratum): total grid MUST be <=256
// or a second scheduling round re-serializes the 166us ldl long pole.
__global__ __launch_bounds__(1024, 4) void ldl_fwd_kernel(
    const float* __restrict__ Ball, const unsigned int* __restrict__ rsmax,
    int* __restrict__ counts,
    const float* __restrict__ x, const float* __restrict__ W1, const float* __restrict__ b1,
    const float* __restrict__ Wb, const float* __restrict__ bb,
    const float* __restrict__ Wl, const float* __restrict__ bl,
    float* __restrict__ out) {
  // LDS union: ldl uses 1536 floats (vrow); forward uses 5184 (4x784 xs + 4x2x256 ybuf)
  __shared__ __align__(16) float smem[4 * 784 + 4 * 2 * NW];
  const int t = threadIdx.x;

  if (blockIdx.x < NLDL) {
    // ================= ldl role (R14-exact) =================
    const int s   = blockIdx.x % NS;
    const int mat = blockIdx.x / NS;
    const int l = t & 63;
    const int w = t >> 6;
    const int rg = l & 31;
    const int ch = 2 * w + (l >> 5);
    const int r0 = rg << 3;
    float* vrow = smem;   // (par*2+row)*384 + idx

    const float h = sqrtf(__uint_as_float(rsmax[mat])) * (1.f / NS);
    const float sg = (s + 1) * h;
    const float mu = sg * sg;

    float Bf[64];
    {
      const float* src = Ball + (size_t)mat * NW * NW + (size_t)r0 * NW + (ch << 3);
#pragma unroll
      for (int i = 0; i < 8; ++i) {
        const float4 a = *(const float4*)(src + i * NW);
        const float4 b = *(const float4*)(src + i * NW + 4);
        Bf[i*8+0] = a.x; Bf[i*8+1] = a.y; Bf[i*8+2] = a.z; Bf[i*8+3] = a.w;
        Bf[i*8+4] = b.x; Bf[i*8+5] = b.y; Bf[i*8+6] = b.z; Bf[i*8+7] = b.w;
      }
    }
    if (rg == ch) {
#pragma unroll
      for (int i = 0; i < 8; ++i) Bf[i*8+i] -= mu;
    }

    if (rg == 0) {
      float* vd0 = &vrow[0 * 384 + ch * PAD];
      float* vd1 = &vrow[1 * 384 + ch * PAD];
      *(float4*)&vd0[0] = make_float4(Bf[0],  Bf[1],  Bf[2],  Bf[3]);
      *(float4*)&vd0[4] = make_float4(Bf[4],  Bf[5],  Bf[6],  Bf[7]);
      *(float4*)&vd1[0] = make_float4(Bf[8],  Bf[9],  Bf[10], Bf[11]);
      *(float4*)&vd1[4] = make_float4(Bf[12], Bf[13], Bf[14], Bf[15]);
    }
    __syncthreads();

    int cnt = 0;
    for (int m = 0; m < NW / 2; ++m) {
      const int k = 2 * m;
      const int par = m & 1;
      const float* v0 = &vrow[(par * 2 + 0) * 384];
      const float* v1 = &vrow[(par * 2 + 1) * 384];

      const int kpos = (k >> 3) * PAD + (k & 7);
      const float2 p01 = *(const float2*)&v0[kpos];
      const float d0  = p01.x;
      const float u01 = p01.y;
      const float e1  = v1[kpos + 1];
      const float d0g = (fabsf(d0) < PIV_EPS) ? copysignf(PIV_EPS, d0) : d0;
      const float i0  = __builtin_amdgcn_rcpf(d0g);
      const float l10 = u01 * i0;
      const float d1  = e1 - l10 * u01;
      const float d1g = (fabsf(d1) < PIV_EPS) ? copysignf(PIV_EPS, d1) : d1;
      const float i1  = __builtin_amdgcn_rcpf(d1g);
      cnt += (d0 < 0.f) ? 1 : 0;
      cnt += (d1 < 0.f) ? 1 : 0;

      if (16 * w + 15 > k) {
        const float4 ra0 = *(const float4*)&v0[rg * PAD + 0];
        const float4 ra1 = *(const float4*)&v0[rg * PAD + 4];
        const float4 rb0 = *(const float4*)&v1[rg * PAD + 0];
        const float4 rb1 = *(const float4*)&v1[rg * PAD + 4];
        const float4 ca0 = *(const float4*)&v0[ch * PAD + 0];
        const float4 ca1 = *(const float4*)&v0[ch * PAD + 4];
        const float4 cb0 = *(const float4*)&v1[ch * PAD + 0];
        const float4 cb1 = *(const float4*)&v1[ch * PAD + 4];
        const float rv0[8] = {ra0.x, ra0.y, ra0.z, ra0.w, ra1.x, ra1.y, ra1.z, ra1.w};
        const float rv1[8] = {rb0.x, rb0.y, rb0.z, rb0.w, rb1.x, rb1.y, rb1.z, rb1.w};
        const float cv0[8] = {ca0.x, ca0.y, ca0.z, ca0.w, ca1.x, ca1.y, ca1.z, ca1.w};
        const float cv1[8] = {cb0.x, cb0.y, cb0.z, cb0.w, cb1.x, cb1.y, cb1.z, cb1.w};

        float g0[8], f1[8];
#pragma unroll
        for (int i = 0; i < 8; ++i) {
          const int r = r0 + i;
          const float f0 = (r > k)     ? -rv0[i] * i0 : 0.f;
          const float v1p = rv1[i] - l10 * rv0[i];
          f1[i] = (r > k + 1) ? -v1p * i1 : 0.f;
          g0[i] = f0 - l10 * f1[i];
        }
#pragma unroll
        for (int i = 0; i < 8; ++i) {
#pragma unroll
          for (int j = 0; j < 8; ++j) {
            Bf[i*8+j] = fmaf(g0[i], cv0[j], fmaf(f1[i], cv1[j], Bf[i*8+j]));
          }
        }
        const int nr = k + 2;
        if (nr < NW && rg == (nr >> 3)) {
          float* vd0 = &vrow[((par ^ 1) * 2 + 0) * 384 + ch * PAD];
          float* vd1 = &vrow[((par ^ 1) * 2 + 1) * 384 + ch * PAD];
          switch (nr & 7) {
            case 0:
              *(float4*)&vd0[0] = make_float4(Bf[0],  Bf[1],  Bf[2],  Bf[3]);
              *(float4*)&vd0[4] = make_float4(Bf[4],  Bf[5],  Bf[6],  Bf[7]);
              *(float4*)&vd1[0] = make_float4(Bf[8],  Bf[9],  Bf[10], Bf[11]);
              *(float4*)&vd1[4] = make_float4(Bf[12], Bf[13], Bf[14], Bf[15]);
              break;
            case 2:
              *(float4*)&vd0[0] = make_float4(Bf[16], Bf[17], Bf[18], Bf[19]);
              *(float4*)&vd0[4] = make_float4(Bf[20], Bf[21], Bf[22], Bf[23]);
              *(float4*)&vd1[0] = make_float4(Bf[24], Bf[25], Bf[26], Bf[27]);
              *(float4*)&vd1[4] = make_float4(Bf[28], Bf[29], Bf[30], Bf[31]);
              break;
            case 4:
              *(float4*)&vd0[0] = make_float4(Bf[32], Bf[33], Bf[34], Bf[35]);
              *(float4*)&vd0[4] = make_float4(Bf[36], Bf[37], Bf[38], Bf[39]);
              *(float4*)&vd1[0] = make_float4(Bf[40], Bf[41], Bf[42], Bf[43]);
              *(float4*)&vd1[4] = make_float4(Bf[44], Bf[45], Bf[46], Bf[47]);
              break;
            default:  // case 6
              *(float4*)&vd0[0] = make_float4(Bf[48], Bf[49], Bf[50], Bf[51]);
              *(float4*)&vd0[4] = make_float4(Bf[52], Bf[53], Bf[54], Bf[55]);
              *(float4*)&vd1[0] = make_float4(Bf[56], Bf[57], Bf[58], Bf[59]);
              *(float4*)&vd1[4] = make_float4(Bf[60], Bf[61], Bf[62], Bf[63]);
              break;
          }
        }
      }
      __syncthreads();
    }

    if (t == 0) counts[mat * NS + s] = cnt;
  } else {
    // ================= forward role: ~11 batches of 4 rows each =================
    const int f = blockIdx.x - NLDL;                 // 0..5
    const int grp = t >> 8;                          // 0..3
    const int o = t & 255;
    float* xs = &smem[grp * 784];
    float* yb = &smem[4 * 784 + grp * 2 * NW];       // [2][NW]

    for (int bt = f; bt < 64; bt += NFWD) {          // 4-row batch index
      const int b = 4 * bt + grp;
      for (int k = o; k < 784; k += 256) xs[k] = x[(size_t)b * 784 + k];
      __syncthreads();
      {
        const float* w1r = W1 + (size_t)o * 784;
        float a0 = 0.f, a1 = 0.f, a2 = 0.f, a3 = 0.f;
        for (int k = 0; k < 784; k += 16) {
          const float4 w0 = *(const float4*)(w1r + k);
          const float4 x0 = *(const float4*)(&xs[k]);
          const float4 w1v = *(const float4*)(w1r + k + 4);
          const float4 x1 = *(const float4*)(&xs[k + 4]);
          const float4 w2 = *(const float4*)(w1r + k + 8);
          const float4 x2 = *(const float4*)(&xs[k + 8]);
          const float4 w3 = *(const float4*)(w1r + k + 12);
          const float4 x3 = *(const float4*)(&xs[k + 12]);
          a0 += w0.x*x0.x + w0.y*x0.y + w0.z*x0.z + w0.w*x0.w;
          a1 += w1v.x*x1.x + w1v.y*x1.y + w1v.z*x1.z + w1v.w*x1.w;
          a2 += w2.x*x2.x + w2.y*x2.y + w2.z*x2.z + w2.w*x2.w;
          a3 += w3.x*x3.x + w3.y*x3.y + w3.z*x3.z + w3.w*x3.w;
        }
        yb[o] = fmaxf(b1[o] + ((a0 + a1) + (a2 + a3)), 0.f);
      }
      __syncthreads();
      int cur = 0;
      for (int d = 0; d < NDEPTH; ++d) {
        const float* wr = Wb + (size_t)d * NW * NW + (size_t)o * NW;
        const float* yc = &yb[cur * NW];
        float a0 = 0.f, a1 = 0.f, a2 = 0.f, a3 = 0.f;
#pragma unroll 4
        for (int k = 0; k < NW; k += 16) {
          const float4 w0 = *(const float4*)(wr + k);
          const float4 y0 = *(const float4*)(&yc[k]);
          const float4 w1v = *(const float4*)(wr + k + 4);
          const float4 y1 = *(const float4*)(&yc[k + 4]);
          const float4 w2 = *(const float4*)(wr + k + 8);
          const float4 y2 = *(const float4*)(&yc[k + 8]);
          const float4 w3 = *(const float4*)(wr + k + 12);
          const float4 y3 = *(const float4*)(&yc[k + 12]);
          a0 += w0.x*y0.x + w0.y*y0.y + w0.z*y0.z + w0.w*y0.w;
          a1 += w1v.x*y1.x + w1v.y*y1.y + w1v.z*y1.z + w1v.w*y1.w;
          a2 += w2.x*y2.x + w2.y*y2.y + w2.z*y2.z + w2.w*y2.w;
          a3 += w3.x*y3.x + w3.y*y3.y + w3.z*y3.z + w3.w*y3.w;
        }
        const float acc = bb[d * NW + o] + ((a0 + a1) + (a2 + a3));
        const float ynew = fmaxf(acc, 0.f) + yc[o];
        yb[(cur ^ 1) * NW + o] = ynew;
        __syncthreads();
        cur ^= 1;
      }
      if (o < 10) {
        const float* wr = Wl + o * NW;
        const float* yc = &yb[cur * NW];
        float a0 = 0.f, a1 = 0.f;
        for (int k = 0; k < NW; k += 8) {
          const float4 w0 = *(const float4*)(wr + k);
          const float4 y0 = *(const float4*)(&yc[k]);
          const float4 w1v = *(const float4*)(wr + k + 4);
          const float4 y1 = *(const float4*)(&yc[k + 4]);
          a0 += w0.x*y0.x + w0.y*y0.y + w0.z*y0.z + w0.w*y0.w;
          a1 += w1v.x*y1.x + w1v.y*y1.y + w1v.z*y1.z + w1v.w*y1.w;
        }
        out[b * 10 + o] = bl[o] + a0 + a1;
      }
      __syncthreads();
    }
  }
}

// ---------------- fused gather + sigma-mean broadcast ----------------
__global__ void gather_out_kernel(const int* __restrict__ counts,
                                  const unsigned int* __restrict__ rsmax,
                                  float* __restrict__ out_all) {
  const int b = blockIdx.x;
  const int j = threadIdx.x;
  __shared__ int cs[NDEPTH * NS];
  if (j < NDEPTH * NS) cs[j] = counts[j];
  __syncthreads();
  float acc = 0.f;
#pragma unroll
  for (int mat = 0; mat < NDEPTH; ++mat) {
    const float h = sqrtf(__uint_as_float(rsmax[mat])) * (1.f / NS);
    int cmax = 0;
    int sstar = NS - 1;
    bool found = false;
    for (int s = 0; s < NS; ++s) {
      cmax = max(cmax, cs[mat * NS + s]);
      if (!found && cmax > (255 - j)) { sstar = s; found = true; }
    }
    acc += (sstar + 0.5f) * h;
  }
  out_all[b * NW + j] = acc * 0.1f;
}

extern "C" void kernel_launch(void* const* d_in, const int* in_sizes, int n_in,
                              void* d_out, int out_size, void* d_ws, size_t ws_size,
                              hipStream_t stream) {
  const float* x  = (const float*)d_in[0];
  const float* W1 = (const float*)d_in[1];
  const float* b1 = (const float*)d_in[2];
  const float* Wb = (const float*)d_in[3];
  const float* bb = (const float*)d_in[4];
  const float* Wl = (const float*)d_in[5];
  const float* bl = (const float*)d_in[6];
  float* out = (float*)d_out;               // 2560 + 65536

  float* ws = (float*)d_ws;
  float* Ball   = ws;                                   // 10*65536 floats
  unsigned int* rsmaxW = (unsigned int*)(ws + 655360);  // 10 uints
  int*   counts = (int*)(ws + 655376);                  // 10*NS ints

  hipMemsetAsync(rsmaxW, 0, NDEPTH * sizeof(unsigned int), stream);
  bmat_kernel<<<dim3(NDEPTH * 32), dim3(256), 0, stream>>>(Wb, Ball, rsmaxW);
  ldl_fwd_kernel<<<dim3(NLDL + NFWD), dim3(1024), 0, stream>>>(
      Ball, rsmaxW, counts, x, W1, b1, Wb, bb, Wl, bl, out);
  gather_out_kernel<<<dim3(256), dim3(256), 0, stream>>>(counts, rsmaxW, out + 2560);
}

// Round 18
// 263.002 us; speedup vs baseline: 14.3059x; 14.3059x over previous
//
#include <hip/hip_runtime.h>
#include <hip/hip_bf16.h>

#define NW 256
#define NDEPTH 10
#define NS 25           // shifts per matrix: 250 ldl WGs = one round at 1 WG/CU
#define PAD 12          // stride 48B: 16B-aligned rows, injective bank-groups
#define PIV_EPS 1e-6f   // LDL tiny-pivot guard

// ---------------- fused bmat + forward (R14-validated; rspart instead of atomic) --------
// blocks [0,320): bmat role -- B = (I+W)^T(I+W); rspart[blk] = max abs-rowsum of its 8 rows
// blocks [320,576): forward role -- one batch row through 12 layers
__global__ __launch_bounds__(256) void bmat_fwd_kernel(
    const float* __restrict__ Wb, float* __restrict__ Ball, float* __restrict__ rspart,
    const float* __restrict__ x, const float* __restrict__ W1, const float* __restrict__ b1,
    const float* __restrict__ bb, const float* __restrict__ Wl, const float* __restrict__ bl,
    float* __restrict__ out) {
  __shared__ __align__(16) float xs[784];
  __shared__ __align__(16) float ybuf[2][NW];
  __shared__ float wsum[4][8];

  if (blockIdx.x < NDEPTH * 32) {
    // ---------------- bmat role ----------------
    const int blk = blockIdx.x;
    const int k   = blk >> 5;
    const int r0  = (blk & 31) << 3;
    const int c   = threadIdx.x;
    const float* W = Wb + (size_t)k * NW * NW;
    float acc[8] = {0.f,0.f,0.f,0.f,0.f,0.f,0.f,0.f};
    for (int j = 0; j < NW; ++j) {
      const float wc = W[j * NW + c];
#pragma unroll
      for (int rr = 0; rr < 8; ++rr) acc[rr] += wc * W[j * NW + r0 + rr];
    }
    float a[8];
#pragma unroll
    for (int rr = 0; rr < 8; ++rr) {
      const int r = r0 + rr;
      const float s = acc[rr] + W[c * NW + r] + W[r * NW + c] + ((r == c) ? 1.f : 0.f);
      Ball[(size_t)k * NW * NW + r * NW + c] = s;
      a[rr] = fabsf(s);
    }
#pragma unroll
    for (int off = 32; off; off >>= 1) {
#pragma unroll
      for (int rr = 0; rr < 8; ++rr) a[rr] += __shfl_down(a[rr], off);
    }
    if ((c & 63) == 0) {
#pragma unroll
      for (int rr = 0; rr < 8; ++rr) wsum[c >> 6][rr] = a[rr];
    }
    __syncthreads();
    if (c == 0) {
      float mx = 0.f;
#pragma unroll
      for (int rr = 0; rr < 8; ++rr)
        mx = fmaxf(mx, wsum[0][rr] + wsum[1][rr] + wsum[2][rr] + wsum[3][rr]);
      rspart[blk] = mx;            // plain store; no memset, no atomic needed
    }
  } else {
    // ---------------- forward role ----------------
    const int b = blockIdx.x - NDEPTH * 32;
    const int o = threadIdx.x;
    for (int k = o; k < 784; k += 256) xs[k] = x[(size_t)b * 784 + k];
    __syncthreads();
    {
      const float* w1r = W1 + (size_t)o * 784;
      float a0 = 0.f, a1 = 0.f, a2 = 0.f, a3 = 0.f;
      for (int k = 0; k < 784; k += 16) {
        const float4 w0 = *(const float4*)(w1r + k);
        const float4 x0 = *(const float4*)(&xs[k]);
        const float4 w1v = *(const float4*)(w1r + k + 4);
        const float4 x1 = *(const float4*)(&xs[k + 4]);
        const float4 w2 = *(const float4*)(w1r + k + 8);
        const float4 x2 = *(const float4*)(&xs[k + 8]);
        const float4 w3 = *(const float4*)(w1r + k + 12);
        const float4 x3 = *(const float4*)(&xs[k + 12]);
        a0 += w0.x*x0.x + w0.y*x0.y + w0.z*x0.z + w0.w*x0.w;
        a1 += w1v.x*x1.x + w1v.y*x1.y + w1v.z*x1.z + w1v.w*x1.w;
        a2 += w2.x*x2.x + w2.y*x2.y + w2.z*x2.z + w2.w*x2.w;
        a3 += w3.x*x3.x + w3.y*x3.y + w3.z*x3.z + w3.w*x3.w;
      }
      ybuf[0][o] = fmaxf(b1[o] + ((a0 + a1) + (a2 + a3)), 0.f);
    }
    __syncthreads();
    int cur = 0;
    for (int d = 0; d < NDEPTH; ++d) {
      const float* wr = Wb + (size_t)d * NW * NW + (size_t)o * NW;
      const float* yc = ybuf[cur];
      float a0 = 0.f, a1 = 0.f, a2 = 0.f, a3 = 0.f;
#pragma unroll 4
      for (int k = 0; k < NW; k += 16) {
        const float4 w0 = *(const float4*)(wr + k);
        const float4 y0 = *(const float4*)(&yc[k]);
        const float4 w1v = *(const float4*)(wr + k + 4);
        const float4 y1 = *(const float4*)(&yc[k + 4]);
        const float4 w2 = *(const float4*)(wr + k + 8);
        const float4 y2 = *(const float4*)(&yc[k + 8]);
        const float4 w3 = *(const float4*)(wr + k + 12);
        const float4 y3 = *(const float4*)(&yc[k + 12]);
        a0 += w0.x*y0.x + w0.y*y0.y + w0.z*y0.z + w0.w*y0.w;
        a1 += w1v.x*y1.x + w1v.y*y1.y + w1v.z*y1.z + w1v.w*y1.w;
        a2 += w2.x*y2.x + w2.y*y2.y + w2.z*y2.z + w2.w*y2.w;
        a3 += w3.x*y3.x + w3.y*y3.y + w3.z*y3.z + w3.w*y3.w;
      }
      const float acc = bb[d * NW + o] + ((a0 + a1) + (a2 + a3));
      const float ynew = fmaxf(acc, 0.f) + yc[o];
      ybuf[cur ^ 1][o] = ynew;
      __syncthreads();
      cur ^= 1;
    }
    if (o < 10) {
      const float* wr = Wl + o * NW;
      const float* yc = ybuf[cur];
      float a0 = 0.f, a1 = 0.f;
      for (int k = 0; k < NW; k += 8) {
        const float4 w0 = *(const float4*)(wr + k);
        const float4 y0 = *(const float4*)(&yc[k]);
        const float4 w1v = *(const float4*)(wr + k + 4);
        const float4 y1 = *(const float4*)(&yc[k + 4]);
        a0 += w0.x*y0.x + w0.y*y0.y + w0.z*y0.z + w0.w*y0.w;
        a1 += w1v.x*y1.x + w1v.y*y1.y + w1v.z*y1.z + w1v.w*y1.w;
      }
      out[b * 10 + o] = bl[o] + a0 + a1;
    }
  }
}

// ---------------- LDL inertia kernel (R14-exact body): rank-2, b128, (1024,4) ----------------
// counts[mat*NS + s] = #negative pivots of LDL^T(B - mu_s I) = #{lambda < mu_s}.
// REGISTER CLIFF (R11/R13/R15 errata): adding live state to this loop spills the
// AGPR-resident Bf tile -> FETCH_SIZE MB->GB, 3-12x slower. Keep rank-2, (1024,4).
// GRID LAW (R16/R17 errata): ldl grid must be <=256 total; forward work needs
// its own wide dispatch (6-CU forward = 3.7ms disaster, R17).
__global__ __launch_bounds__(1024, 4) void ldl_kernel(const float* __restrict__ Ball,
                                                      const float* __restrict__ rspart,
                                                      int* __restrict__ counts) {
  const int s   = blockIdx.x;
  const int mat = blockIdx.y;
  const int t = threadIdx.x;
  const int l = t & 63;
  const int w = t >> 6;              // wave 0..15
  const int rg = l & 31;             // row group: rows [8rg, 8rg+8)
  const int ch = 2 * w + (l >> 5);   // col chunk: cols [8ch, 8ch+8)
  const int r0 = rg << 3;

  __shared__ __align__(16) float vrow[2][2][32 * PAD];   // [m-parity][row k+0/k+1]

  float rs = 0.f;
#pragma unroll
  for (int p = 0; p < 32; ++p) rs = fmaxf(rs, rspart[mat * 32 + p]);
  const float h = sqrtf(rs) * (1.f / NS);
  const float sg = (s + 1) * h;
  const float mu = sg * sg;

  float Bf[64];   // row r0+i, col c0+j at Bf[i*8+j]
  {
    const float* src = Ball + (size_t)mat * NW * NW + (size_t)r0 * NW + (ch << 3);
#pragma unroll
    for (int i = 0; i < 8; ++i) {
      const float4 a = *(const float4*)(src + i * NW);
      const float4 b = *(const float4*)(src + i * NW + 4);
      Bf[i*8+0] = a.x; Bf[i*8+1] = a.y; Bf[i*8+2] = a.z; Bf[i*8+3] = a.w;
      Bf[i*8+4] = b.x; Bf[i*8+5] = b.y; Bf[i*8+6] = b.z; Bf[i*8+7] = b.w;
    }
  }
  if (rg == ch) {
#pragma unroll
    for (int i = 0; i < 8; ++i) Bf[i*8+i] -= mu;
  }

  // initial dump: rows 0 and 1 (= columns 0,1), parity 0
  if (rg == 0) {
    float* vd0 = &vrow[0][0][ch * PAD];
    float* vd1 = &vrow[0][1][ch * PAD];
    *(float4*)&vd0[0] = make_float4(Bf[0],  Bf[1],  Bf[2],  Bf[3]);
    *(float4*)&vd0[4] = make_float4(Bf[4],  Bf[5],  Bf[6],  Bf[7]);
    *(float4*)&vd1[0] = make_float4(Bf[8],  Bf[9],  Bf[10], Bf[11]);
    *(float4*)&vd1[4] = make_float4(Bf[12], Bf[13], Bf[14], Bf[15]);
  }
  __syncthreads();

  int cnt = 0;
  for (int m = 0; m < NW / 2; ++m) {
    const int k = 2 * m;
    const int par = m & 1;
    const float* v0 = vrow[par][0];
    const float* v1 = vrow[par][1];

    const int kpos = (k >> 3) * PAD + (k & 7);      // k even -> 8B-aligned
    const float2 p01 = *(const float2*)&v0[kpos];
    const float d0  = p01.x;
    const float u01 = p01.y;
    const float e1  = v1[kpos + 1];
    const float d0g = (fabsf(d0) < PIV_EPS) ? copysignf(PIV_EPS, d0) : d0;
    const float i0  = __builtin_amdgcn_rcpf(d0g);
    const float l10 = u01 * i0;
    const float d1  = e1 - l10 * u01;
    const float d1g = (fabsf(d1) < PIV_EPS) ? copysignf(PIV_EPS, d1) : d1;
    const float i1  = __builtin_amdgcn_rcpf(d1g);
    cnt += (d0 < 0.f) ? 1 : 0;
    cnt += (d1 < 0.f) ? 1 : 0;

    if (16 * w + 15 > k) {            // wave has live columns
      const float4 ra0 = *(const float4*)&v0[rg * PAD + 0];
      const float4 ra1 = *(const float4*)&v0[rg * PAD + 4];
      const float4 rb0 = *(const float4*)&v1[rg * PAD + 0];
      const float4 rb1 = *(const float4*)&v1[rg * PAD + 4];
      const float4 ca0 = *(const float4*)&v0[ch * PAD + 0];
      const float4 ca1 = *(const float4*)&v0[ch * PAD + 4];
      const float4 cb0 = *(const float4*)&v1[ch * PAD + 0];
      const float4 cb1 = *(const float4*)&v1[ch * PAD + 4];
      const float rv0[8] = {ra0.x, ra0.y, ra0.z, ra0.w, ra1.x, ra1.y, ra1.z, ra1.w};
      const float rv1[8] = {rb0.x, rb0.y, rb0.z, rb0.w, rb1.x, rb1.y, rb1.z, rb1.w};
      const float cv0[8] = {ca0.x, ca0.y, ca0.z, ca0.w, ca1.x, ca1.y, ca1.z, ca1.w};
      const float cv1[8] = {cb0.x, cb0.y, cb0.z, cb0.w, cb1.x, cb1.y, cb1.z, cb1.w};

      float g0[8], f1[8];
#pragma unroll
      for (int i = 0; i < 8; ++i) {
        const int r = r0 + i;
        const float f0 = (r > k)     ? -rv0[i] * i0 : 0.f;
        const float v1p = rv1[i] - l10 * rv0[i];
        f1[i] = (r > k + 1) ? -v1p * i1 : 0.f;
        g0[i] = f0 - l10 * f1[i];
      }
#pragma unroll
      for (int i = 0; i < 8; ++i) {
#pragma unroll
        for (int j = 0; j < 8; ++j) {
          Bf[i*8+j] = fmaf(g0[i], cv0[j], fmaf(f1[i], cv1[j], Bf[i*8+j]));
        }
      }
      const int nr = k + 2;
      if (nr < NW && rg == (nr >> 3)) {
        float* vd0 = &vrow[par ^ 1][0][ch * PAD];
        float* vd1 = &vrow[par ^ 1][1][ch * PAD];
        switch (nr & 7) {
          case 0:
            *(float4*)&vd0[0] = make_float4(Bf[0],  Bf[1],  Bf[2],  Bf[3]);
            *(float4*)&vd0[4] = make_float4(Bf[4],  Bf[5],  Bf[6],  Bf[7]);
            *(float4*)&vd1[0] = make_float4(Bf[8],  Bf[9],  Bf[10], Bf[11]);
            *(float4*)&vd1[4] = make_float4(Bf[12], Bf[13], Bf[14], Bf[15]);
            break;
          case 2:
            *(float4*)&vd0[0] = make_float4(Bf[16], Bf[17], Bf[18], Bf[19]);
            *(float4*)&vd0[4] = make_float4(Bf[20], Bf[21], Bf[22], Bf[23]);
            *(float4*)&vd1[0] = make_float4(Bf[24], Bf[25], Bf[26], Bf[27]);
            *(float4*)&vd1[4] = make_float4(Bf[28], Bf[29], Bf[30], Bf[31]);
            break;
          case 4:
            *(float4*)&vd0[0] = make_float4(Bf[32], Bf[33], Bf[34], Bf[35]);
            *(float4*)&vd0[4] = make_float4(Bf[36], Bf[37], Bf[38], Bf[39]);
            *(float4*)&vd1[0] = make_float4(Bf[40], Bf[41], Bf[42], Bf[43]);
            *(float4*)&vd1[4] = make_float4(Bf[44], Bf[45], Bf[46], Bf[47]);
            break;
          default:  // case 6
            *(float4*)&vd0[0] = make_float4(Bf[48], Bf[49], Bf[50], Bf[51]);
            *(float4*)&vd0[4] = make_float4(Bf[52], Bf[53], Bf[54], Bf[55]);
            *(float4*)&vd1[0] = make_float4(Bf[56], Bf[57], Bf[58], Bf[59]);
            *(float4*)&vd1[4] = make_float4(Bf[60], Bf[61], Bf[62], Bf[63]);
            break;
        }
      }
    }
    __syncthreads();
  }

  if (t == 0) counts[mat * NS + s] = cnt;
}

// ---------------- fused gather + sigma-mean broadcast ----------------
__global__ void gather_out_kernel(const int* __restrict__ counts,
                                  const float* __restrict__ rspart,
                                  float* __restrict__ out_all) {
  const int b = blockIdx.x;
  const int j = threadIdx.x;
  __shared__ int cs[NDEPTH * NS];
  __shared__ float hs[NDEPTH];
  if (j < NDEPTH * NS) cs[j] = counts[j];
  if (j < NDEPTH) {
    float rs = 0.f;
#pragma unroll
    for (int p = 0; p < 32; ++p) rs = fmaxf(rs, rspart[j * 32 + p]);
    hs[j] = sqrtf(rs) * (1.f / NS);
  }
  __syncthreads();
  float acc = 0.f;
#pragma unroll
  for (int mat = 0; mat < NDEPTH; ++mat) {
    const float h = hs[mat];
    int cmax = 0;
    int sstar = NS - 1;
    bool found = false;
    for (int s = 0; s < NS; ++s) {
      cmax = max(cmax, cs[mat * NS + s]);
      if (!found && cmax > (255 - j)) { sstar = s; found = true; }
    }
    acc += (sstar + 0.5f) * h;
  }
  out_all[b * NW + j] = acc * 0.1f;
}

extern "C" void kernel_launch(void* const* d_in, const int* in_sizes, int n_in,
                              void* d_out, int out_size, void* d_ws, size_t ws_size,
                              hipStream_t stream) {
  const float* x  = (const float*)d_in[0];
  const float* W1 = (const float*)d_in[1];
  const float* b1 = (const float*)d_in[2];
  const float* Wb = (const float*)d_in[3];
  const float* bb = (const float*)d_in[4];
  const float* Wl = (const float*)d_in[5];
  const float* bl = (const float*)d_in[6];
  float* out = (float*)d_out;               // 2560 + 65536

  float* ws = (float*)d_ws;
  float* Ball   = ws;                        // 10*65536 floats
  float* rspart = ws + 655360;               // 320 floats
  int*   counts = (int*)(ws + 655680);       // 10*NS ints

  bmat_fwd_kernel<<<dim3(NDEPTH * 32 + 256), dim3(256), 0, stream>>>(
      Wb, Ball, rspart, x, W1, b1, bb, Wl, bl, out);
  ldl_kernel<<<dim3(NS, NDEPTH), dim3(1024), 0, stream>>>(Ball, rspart, counts);
  gather_out_kernel<<<dim3(256), dim3(256), 0, stream>>>(counts, rspart, out + 2560);
}